// Round 6
// baseline (948.382 us; speedup 1.0000x reference)
//
#include <hip/hip_runtime.h>
#include <stdint.h>

// CrossStreamAttention: B=32768, D=512, H=8, S=3, DH=64
// R6: single-chunk (Bc=32768, scratch 208MB) pipeline:
//   pack3 -> qkv_attn (fused gemm+attention) -> proj_gate (gemm+residual+gate,
//   G in-place over S) -> gemm_bt<SILU> (mlp1) -> mlp2_ln (gemm+LayerNorm).
// gate3 / lnorm passes and AT/F buffers eliminated.

typedef float f32x4 __attribute__((ext_vector_type(4)));
typedef short bf16x8 __attribute__((ext_vector_type(8)));  // 8 bf16 in 4 VGPRs

__device__ __forceinline__ float bf2f(unsigned short h) {
  return __uint_as_float(((unsigned)h) << 16);
}
__device__ __forceinline__ unsigned short f2bf(float f) {
  unsigned u = __float_as_uint(f);
  u += 0x7FFFu + ((u >> 16) & 1u);   // RNE
  return (unsigned short)(u >> 16);
}
__device__ __forceinline__ ushort4 f2bf4(float4 v) {
  return make_ushort4(f2bf(v.x), f2bf(v.y), f2bf(v.z), f2bf(v.w));
}

__device__ __forceinline__ void async_cp16(const void* g, void* lds) {
  __builtin_amdgcn_global_load_lds(
      (const __attribute__((address_space(1))) void*)g,
      (__attribute__((address_space(3))) void*)lds, 16, 0, 0);
}

// ---------------------------------------------------------------- converts
__global__ void __launch_bounds__(256) cvtbf(const float4* __restrict__ src,
                                             ushort4* __restrict__ dst, int n4) {
  int i = blockIdx.x * 256 + threadIdx.x;
  if (i < n4) dst[i] = f2bf4(src[i]);
}

// pack stacked[b,s,:] = input_s[b,:], bf16.
__global__ void __launch_bounds__(256) pack3(const float4* __restrict__ X0,
                                             const float4* __restrict__ X1,
                                             const float4* __restrict__ X2,
                                             ushort4* __restrict__ S) {
  int tid = blockIdx.x * 256 + threadIdx.x;   // b*128 + c
  int b = tid >> 7, c = tid & 127;
  long base = (long)(3 * b) * 128 + c;
  S[base]       = f2bf4(X0[tid]);
  S[base + 128] = f2bf4(X1[tid]);
  S[base + 256] = f2bf4(X2[tid]);
}

// ---------------------------------------------------------------- fused QKV gemm + attention
// grid (8, ny). 96 rows x 192 cols (q|k|v of head h). XCD-grouped remap.
__global__ void __launch_bounds__(256)
qkv_attn(const unsigned short* __restrict__ S,   // [3Bc,512]
         const unsigned short* __restrict__ Wi,  // [1536,512]
         const float* __restrict__ bin,          // [1536]
         unsigned short* __restrict__ AO) {      // [3Bc,512]
  __shared__ unsigned short lds[96 * 200];       // 38400 B; union staging/C
  unsigned short* Abuf = lds;                    // [96][64] during K-loop
  unsigned short* Bbuf = lds + 6144;             // [192][64] during K-loop

  const int t = threadIdx.x;
  const int lane = t & 63;
  const int wave = t >> 6;
  const int wm = wave >> 1, wn = wave & 1;

  const int ny = gridDim.y;
  const int id = blockIdx.y * 8 + blockIdx.x;
  const int xcd = id & 7, j = id >> 3;
  const int h = j & 7;
  const long m0 = (long)(xcd * (ny >> 3) + (j >> 3)) * 96;

  const int trow = t >> 3;
  const int swz = ((t & 7) ^ (trow & 7)) << 3;
  const unsigned short* Ag = S + (m0 + trow) * 512 + swz;
  const unsigned short* Bg = Wi + ((long)h * 64 + trow) * 512 + swz;
  unsigned short* AsD = Abuf + t * 8;
  unsigned short* BsD = Bbuf + t * 8;

  f32x4 acc[3][6] = {};
  const int arow0 = wm * 48 + (lane & 15);
  const int brow0 = wn * 96 + (lane & 15);

  for (int k0 = 0; k0 < 512; k0 += 64) {
    __syncthreads();
#pragma unroll
    for (int r = 0; r < 3; r++)
      async_cp16(Ag + (long)r * 32 * 512 + k0, AsD + r * 2048);
#pragma unroll
    for (int r = 0; r < 6; r++)
      async_cp16(Bg + (long)((r >> 1) * 512 + (r & 1) * 32) * 512 + k0, BsD + r * 2048);
    __syncthreads();
#pragma unroll
    for (int kk = 0; kk < 2; kk++) {
      const int sc = ((kk * 4 + (lane >> 4)) ^ (lane & 7)) << 3;
      bf16x8 af[3], bfr[6];
#pragma unroll
      for (int mt = 0; mt < 3; mt++)
        af[mt] = *(const bf16x8*)&Abuf[(arow0 + mt * 16) * 64 + sc];
#pragma unroll
      for (int nt = 0; nt < 6; nt++)
        bfr[nt] = *(const bf16x8*)&Bbuf[(brow0 + nt * 16) * 64 + sc];
#pragma unroll
      for (int mt = 0; mt < 3; mt++)
#pragma unroll
        for (int nt = 0; nt < 6; nt++)
          acc[mt][nt] = __builtin_amdgcn_mfma_f32_16x16x32_bf16(
              af[mt], bfr[nt], acc[mt][nt], 0, 0, 0);
    }
  }

  // dump C (+bias) as bf16 into LDS, stride 200
  __syncthreads();
  const int crow0 = wm * 48 + ((lane >> 4) << 2);
  const int ccol0 = wn * 96 + (lane & 15);
#pragma unroll
  for (int nt = 0; nt < 6; nt++) {
    const int col = ccol0 + nt * 16;                 // 0..191
    const float bv = bin[(col >> 6) * 512 + h * 64 + (col & 63)];
#pragma unroll
    for (int mt = 0; mt < 3; mt++)
#pragma unroll
      for (int r = 0; r < 4; r++)
        lds[(crow0 + mt * 16 + r) * 200 + col] = f2bf(acc[mt][nt][r] + bv);
  }
  __syncthreads();

  // attention: wave handles 8 b's; lane = bi*8 + l8; lane owns d = l8*8..+7
  const int bi = lane >> 3;
  const int l8 = lane & 7;
  const int r0 = (wave * 8 + bi) * 3;
  float q[3][8], k[3][8], v[3][8];
#pragma unroll
  for (int s = 0; s < 3; s++) {
    const unsigned short* rowp = &lds[(r0 + s) * 200 + l8 * 8];
    uint4 qu = *(const uint4*)(rowp);
    uint4 ku = *(const uint4*)(rowp + 64);
    uint4 vu = *(const uint4*)(rowp + 128);
    const unsigned* qw = (const unsigned*)&qu;
    const unsigned* kw = (const unsigned*)&ku;
    const unsigned* vw = (const unsigned*)&vu;
#pragma unroll
    for (int jj = 0; jj < 4; jj++) {
      q[s][2 * jj]     = __uint_as_float(qw[jj] << 16);
      q[s][2 * jj + 1] = __uint_as_float(qw[jj] & 0xffff0000u);
      k[s][2 * jj]     = __uint_as_float(kw[jj] << 16);
      k[s][2 * jj + 1] = __uint_as_float(kw[jj] & 0xffff0000u);
      v[s][2 * jj]     = __uint_as_float(vw[jj] << 16);
      v[s][2 * jj + 1] = __uint_as_float(vw[jj] & 0xffff0000u);
    }
  }
  float p[3][3];
#pragma unroll
  for (int s = 0; s < 3; s++)
#pragma unroll
    for (int u = 0; u < 3; u++) {
      float d = 0.f;
#pragma unroll
      for (int e = 0; e < 8; e++) d = fmaf(q[s][e], k[u][e], d);
      p[s][u] = d;
    }
#pragma unroll
  for (int m = 1; m < 8; m <<= 1)
#pragma unroll
    for (int s = 0; s < 3; s++)
#pragma unroll
      for (int u = 0; u < 3; u++) p[s][u] += __shfl_xor(p[s][u], m, 64);

  unsigned short* ob = AO + (m0 + r0) * 512 + h * 64 + l8 * 8;
#pragma unroll
  for (int s = 0; s < 3; s++) {
    float a0 = p[s][0] * 0.125f, a1 = p[s][1] * 0.125f, a2 = p[s][2] * 0.125f;
    float mx = fmaxf(a0, fmaxf(a1, a2));
    float e0 = __expf(a0 - mx), e1 = __expf(a1 - mx), e2 = __expf(a2 - mx);
    float inv = 1.0f / (e0 + e1 + e2);
    unsigned ow[4];
#pragma unroll
    for (int jj = 0; jj < 4; jj++) {
      float lo = (e0 * v[0][2 * jj] + e1 * v[1][2 * jj] + e2 * v[2][2 * jj]) * inv;
      float hi = (e0 * v[0][2 * jj + 1] + e1 * v[1][2 * jj + 1] + e2 * v[2][2 * jj + 1]) * inv;
      ow[jj] = (unsigned)f2bf(lo) | ((unsigned)f2bf(hi) << 16);
    }
    *(uint4*)(ob + s * 512) = *(uint4*)ow;
  }
}

// ---------------------------------------------------------------- proj + residual + gate
// Block: 48 M-rows (16 gate rows) x N=512 (full), K=512, BK=32, 4 waves (1x4).
// W_out LDS-staged (source-XOR swizzle, linear lane*16 dest); A-frags direct
// global b128. Epilogue: bias+residual in-reg, gate dots (16-lane shuffle +
// LDS cross-wave), softmax, scaled bf16 write. G may alias Sres (lane reads
// exactly the elements it writes).
__global__ void __launch_bounds__(256)
proj_gate(const unsigned short* __restrict__ AO,    // [3Bc,512]
          const unsigned short* Sres,               // [3Bc,512]
          const unsigned short* __restrict__ Wo,    // [512,512]
          const float* __restrict__ bo,             // [512]
          const float* __restrict__ WG,             // [3,1536]
          const float* __restrict__ BG,             // [3]
          unsigned short* G) {                      // [3Bc,512] (alias Sres ok)
  __shared__ unsigned short Bs[512 * 32];           // 32 KB
  __shared__ float gpart[48][4][3];
  __shared__ float gates[16][3];
  const int t = threadIdx.x;
  const int lane = t & 63;
  const int w = t >> 6;
  const long m0 = (long)blockIdx.x * 48;
  const int ar = lane & 15, aq = lane >> 4;

  f32x4 acc[3][8] = {};
  for (int k0 = 0; k0 < 512; k0 += 32) {
    __syncthreads();
#pragma unroll
    for (int i = 0; i < 8; i++) {
      const int c = i * 256 + t;
      const int row = c >> 2, slot = c & 3;
      const int chunk = slot ^ ((row >> 1) & 3);
      async_cp16(Wo + row * 512 + k0 + chunk * 8, Bs + c * 8);
    }
    bf16x8 af[3];
#pragma unroll
    for (int mt = 0; mt < 3; mt++)
      af[mt] = *(const bf16x8*)(AO + (m0 + mt * 16 + ar) * 512 + k0 + aq * 8);
    __syncthreads();
    bf16x8 bfr[8];
#pragma unroll
    for (int nt = 0; nt < 8; nt++) {
      const int br = w * 128 + nt * 16 + ar;
      bfr[nt] = *(const bf16x8*)&Bs[br * 32 + ((aq ^ ((br >> 1) & 3)) << 3)];
    }
#pragma unroll
    for (int mt = 0; mt < 3; mt++)
#pragma unroll
      for (int nt = 0; nt < 8; nt++)
        acc[mt][nt] = __builtin_amdgcn_mfma_f32_16x16x32_bf16(
            af[mt], bfr[nt], acc[mt][nt], 0, 0, 0);
  }

  // bias + residual (in-register)
#pragma unroll
  for (int nt = 0; nt < 8; nt++) {
    const int col = w * 128 + nt * 16 + ar;
    const float bv = bo[col];
#pragma unroll
    for (int mt = 0; mt < 3; mt++)
#pragma unroll
      for (int r = 0; r < 4; r++) {
        const int crow = mt * 16 + aq * 4 + r;
        acc[mt][nt][r] += bv + bf2f(Sres[(m0 + crow) * 512 + col]);
      }
  }
  // gate partial dots per row
#pragma unroll
  for (int mt = 0; mt < 3; mt++)
#pragma unroll
    for (int r = 0; r < 4; r++) {
      const int crow = mt * 16 + aq * 4 + r;
      const int s = crow % 3;
      float p0 = 0.f, p1 = 0.f, p2 = 0.f;
#pragma unroll
      for (int nt = 0; nt < 8; nt++) {
        const int col = w * 128 + nt * 16 + ar;
        const float vv = acc[mt][nt][r];
        const float* wg = WG + s * 512 + col;
        p0 = fmaf(vv, wg[0], p0);
        p1 = fmaf(vv, wg[1536], p1);
        p2 = fmaf(vv, wg[3072], p2);
      }
#pragma unroll
      for (int msk = 1; msk < 16; msk <<= 1) {
        p0 += __shfl_xor(p0, msk, 64);
        p1 += __shfl_xor(p1, msk, 64);
        p2 += __shfl_xor(p2, msk, 64);
      }
      if (ar == 0) {
        gpart[crow][w][0] = p0; gpart[crow][w][1] = p1; gpart[crow][w][2] = p2;
      }
    }
  __syncthreads();
  if (t < 16) {
    float l0 = BG[0], l1 = BG[1], l2 = BG[2];
    for (int s = 0; s < 3; s++)
      for (int ww = 0; ww < 4; ww++) {
        l0 += gpart[t * 3 + s][ww][0];
        l1 += gpart[t * 3 + s][ww][1];
        l2 += gpart[t * 3 + s][ww][2];
      }
    float mx = fmaxf(l0, fmaxf(l1, l2));
    l0 = __expf(l0 - mx); l1 = __expf(l1 - mx); l2 = __expf(l2 - mx);
    float inv = 1.0f / (l0 + l1 + l2);
    gates[t][0] = l0 * inv; gates[t][1] = l1 * inv; gates[t][2] = l2 * inv;
  }
  __syncthreads();
#pragma unroll
  for (int mt = 0; mt < 3; mt++)
#pragma unroll
    for (int r = 0; r < 4; r++) {
      const int crow = mt * 16 + aq * 4 + r;
      const float gv = gates[crow / 3][crow % 3];
#pragma unroll
      for (int nt = 0; nt < 8; nt++) {
        const int col = w * 128 + nt * 16 + ar;
        G[(m0 + crow) * 512 + col] = f2bf(acc[mt][nt][r] * gv);
      }
    }
}

// ---------------------------------------------------------------- mlp2 + LayerNorm
// Block: 64 rows x N=512 (full), K=1024, BK=32, 8 waves (2x4). Same staging
// scheme as proj_gate. Epilogue: bias, LN stats (16-lane shuffle + LDS
// cross-wave), normalize, f32 write to d_out.
__global__ void __launch_bounds__(512)
mlp2_ln(const unsigned short* __restrict__ H,     // [Bc,1024]
        const unsigned short* __restrict__ W2,    // [512,1024]
        const float* __restrict__ b2,             // [512]
        const float* __restrict__ gamma,          // [512]
        const float* __restrict__ beta,           // [512]
        float* __restrict__ out) {                // [Bc,512]
  __shared__ unsigned short Bs[512 * 32];         // 32 KB
  __shared__ float stats[64][4][2];
  __shared__ float mv[64][2];
  const int t = threadIdx.x;
  const int lane = t & 63;
  const int w = t >> 6;
  const int wm = w >> 2, wn = w & 3;
  const long m0 = (long)blockIdx.x * 64;
  const int ar = lane & 15, aq = lane >> 4;

  f32x4 acc[2][8] = {};
  for (int k0 = 0; k0 < 1024; k0 += 32) {
    __syncthreads();
#pragma unroll
    for (int i = 0; i < 4; i++) {
      const int c = i * 512 + t;
      const int row = c >> 2, slot = c & 3;
      const int chunk = slot ^ ((row >> 1) & 3);
      async_cp16(W2 + row * 1024 + k0 + chunk * 8, Bs + c * 8);
    }
    bf16x8 af[2];
#pragma unroll
    for (int mt = 0; mt < 2; mt++)
      af[mt] = *(const bf16x8*)(H + (m0 + wm * 32 + mt * 16 + ar) * 1024 + k0 + aq * 8);
    __syncthreads();
    bf16x8 bfr[8];
#pragma unroll
    for (int nt = 0; nt < 8; nt++) {
      const int br = wn * 128 + nt * 16 + ar;
      bfr[nt] = *(const bf16x8*)&Bs[br * 32 + ((aq ^ ((br >> 1) & 3)) << 3)];
    }
#pragma unroll
    for (int mt = 0; mt < 2; mt++)
#pragma unroll
      for (int nt = 0; nt < 8; nt++)
        acc[mt][nt] = __builtin_amdgcn_mfma_f32_16x16x32_bf16(
            af[mt], bfr[nt], acc[mt][nt], 0, 0, 0);
  }

  // bias + LN partial stats
#pragma unroll
  for (int nt = 0; nt < 8; nt++) {
    const float bv = b2[wn * 128 + nt * 16 + ar];
#pragma unroll
    for (int mt = 0; mt < 2; mt++)
#pragma unroll
      for (int r = 0; r < 4; r++) acc[mt][nt][r] += bv;
  }
#pragma unroll
  for (int mt = 0; mt < 2; mt++)
#pragma unroll
    for (int r = 0; r < 4; r++) {
      const int crow = wm * 32 + mt * 16 + aq * 4 + r;
      float s = 0.f, ss = 0.f;
#pragma unroll
      for (int nt = 0; nt < 8; nt++) {
        const float vv = acc[mt][nt][r];
        s += vv; ss = fmaf(vv, vv, ss);
      }
#pragma unroll
      for (int msk = 1; msk < 16; msk <<= 1) {
        s += __shfl_xor(s, msk, 64);
        ss += __shfl_xor(ss, msk, 64);
      }
      if (ar == 0) { stats[crow][wn][0] = s; stats[crow][wn][1] = ss; }
    }
  __syncthreads();
  if (t < 64) {
    float s = stats[t][0][0] + stats[t][1][0] + stats[t][2][0] + stats[t][3][0];
    float ss = stats[t][0][1] + stats[t][1][1] + stats[t][2][1] + stats[t][3][1];
    float mean = s * (1.0f / 512.0f);
    float var = ss * (1.0f / 512.0f) - mean * mean;
    mv[t][0] = mean;
    mv[t][1] = rsqrtf(var + 1e-5f);
  }
  __syncthreads();
#pragma unroll
  for (int mt = 0; mt < 2; mt++)
#pragma unroll
    for (int r = 0; r < 4; r++) {
      const int crow = wm * 32 + mt * 16 + aq * 4 + r;
      const float mean = mv[crow][0], rstd = mv[crow][1];
#pragma unroll
      for (int nt = 0; nt < 8; nt++) {
        const int col = wn * 128 + nt * 16 + ar;
        out[(m0 + crow) * 512 + col] =
            (acc[mt][nt][r] - mean) * rstd * gamma[col] + beta[col];
      }
    }
}

// ---------------------------------------------------------------- GEMM (mlp1)
// C[M,N] = A[M,K] @ W[N,K]^T + bias. 128x128 tile, BK=64, 4 waves (2x2).
enum { EPI_BF16 = 0, EPI_RES = 1, EPI_SILU = 2, EPI_F32 = 3 };

template <int EPI>
__global__ void __launch_bounds__(256)
gemm_bt(const unsigned short* __restrict__ A,
        const unsigned short* __restrict__ W,
        const float* __restrict__ bias,
        const unsigned short* __restrict__ Res,
        void* __restrict__ Out,
        int K, int N) {
  __shared__ unsigned short As[128 * 64];
  __shared__ unsigned short Bs[128 * 64];
  const int t = threadIdx.x;
  const int lane = t & 63;
  const int wave = t >> 6;
  const int wm = wave >> 1, wn = wave & 1;

  const int nb = gridDim.x;
  const int nblocks = nb * gridDim.y;
  const int id = blockIdx.y * nb + blockIdx.x;
  const int lid = ((nblocks & 7) == 0) ? ((id & 7) * (nblocks >> 3) + (id >> 3)) : id;
  const long bm = (long)(lid / nb) * 128;
  const long bn = (long)(lid % nb) * 128;

  const int srow = t >> 3;
  const int schunk = ((t & 7) ^ (srow & 7)) << 3;
  const unsigned short* Ag = A + (bm + srow) * (long)K + schunk;
  const unsigned short* Wg = W + (bn + srow) * (long)K + schunk;
  unsigned short* AsD = As + t * 8;
  unsigned short* BsD = Bs + t * 8;

  f32x4 acc[4][4] = {};
  const int arow0 = wm * 64 + (lane & 15);
  const int brow0 = wn * 64 + (lane & 15);

  for (int k0 = 0; k0 < K; k0 += 64) {
    __syncthreads();
#pragma unroll
    for (int i = 0; i < 4; i++) {
      async_cp16(Ag + (long)(i * 32) * K + k0, AsD + i * 2048);
      async_cp16(Wg + (long)(i * 32) * K + k0, BsD + i * 2048);
    }
    __syncthreads();
#pragma unroll
    for (int kk = 0; kk < 2; kk++) {
      const int sc = ((kk * 4 + (lane >> 4)) ^ (lane & 7)) << 3;
      bf16x8 af[4], bfr[4];
#pragma unroll
      for (int mt = 0; mt < 4; mt++)
        af[mt] = *(const bf16x8*)&As[(arow0 + mt * 16) * 64 + sc];
#pragma unroll
      for (int nt = 0; nt < 4; nt++)
        bfr[nt] = *(const bf16x8*)&Bs[(brow0 + nt * 16) * 64 + sc];
#pragma unroll
      for (int mt = 0; mt < 4; mt++)
#pragma unroll
        for (int nt = 0; nt < 4; nt++)
          acc[mt][nt] = __builtin_amdgcn_mfma_f32_16x16x32_bf16(
              af[mt], bfr[nt], acc[mt][nt], 0, 0, 0);
    }
  }

  const long row0 = bm + wm * 64 + ((lane >> 4) << 2);
  const int col0 = (int)bn + wn * 64 + (lane & 15);
#pragma unroll
  for (int nt = 0; nt < 4; nt++) {
    const int col = col0 + nt * 16;
    const float bv = bias[col];
#pragma unroll
    for (int mt = 0; mt < 4; mt++) {
      const long rbase = row0 + mt * 16;
#pragma unroll
      for (int r = 0; r < 4; r++) {
        float v = acc[mt][nt][r] + bv;
        const long idx = (rbase + r) * (long)N + col;
        if (EPI == EPI_RES) v += bf2f(Res[idx]);
        if (EPI == EPI_SILU) v = v * (1.0f / (1.0f + __expf(-v)));
        if (EPI == EPI_F32)
          ((float*)Out)[idx] = v;
        else
          ((unsigned short*)Out)[idx] = f2bf(v);
      }
    }
  }
}

// ---------------------------------------------------------------- launch
extern "C" void kernel_launch(void* const* d_in, const int* in_sizes, int n_in,
                              void* d_out, int out_size, void* d_ws, size_t ws_size,
                              hipStream_t stream) {
  const float* kin    = (const float*)d_in[0];
  const float* colr   = (const float*)d_in[1];
  const float* spi    = (const float*)d_in[2];
  const float* w_in   = (const float*)d_in[3];
  const float* b_in   = (const float*)d_in[4];
  const float* w_out  = (const float*)d_in[5];
  const float* b_out  = (const float*)d_in[6];
  const float* w_gate = (const float*)d_in[7];
  const float* b_gate = (const float*)d_in[8];
  const float* w1     = (const float*)d_in[9];
  const float* b1     = (const float*)d_in[10];
  const float* w2     = (const float*)d_in[11];
  const float* b2     = (const float*)d_in[12];
  const float* gamma  = (const float*)d_in[13];
  const float* beta   = (const float*)d_in[14];
  float* out = (float*)d_out;

  // scratch: weights 6,291,456 + S(3072*Bc, reused as G in-place) + AO(3072*Bc)
  long Bc = 32768;
  while (Bc > 1024 && (size_t)(6291456 + 6144 * Bc) > ws_size) Bc >>= 1;
  const int nch = (int)(32768 / Bc);

  char* ws = (char*)d_ws;
  unsigned short* Wic = (unsigned short*)(ws);              // w_in  1536x512
  unsigned short* Woc = (unsigned short*)(ws + 1572864);    // w_out 512x512
  unsigned short* W1c = (unsigned short*)(ws + 2097152);    // w1    1024x1536
  unsigned short* W2c = (unsigned short*)(ws + 5242880);    // w2    512x1024
  char* Sb  = ws + 6291456;                                 // S/G [3Bc,512] bf16
  char* AOb = Sb + 3072 * Bc;                               // AO/H buffer

  cvtbf<<<768, 256, 0, stream>>>((const float4*)w_in, (ushort4*)Wic, 196608);
  cvtbf<<<256, 256, 0, stream>>>((const float4*)w_out, (ushort4*)Woc, 65536);
  cvtbf<<<1536, 256, 0, stream>>>((const float4*)w1, (ushort4*)W1c, 393216);
  cvtbf<<<512, 256, 0, stream>>>((const float4*)w2, (ushort4*)W2c, 131072);

  for (int c = 0; c < nch; c++) {
    const long boff = (long)c * Bc;
    unsigned short* S_c  = (unsigned short*)Sb;
    unsigned short* AO_c = (unsigned short*)AOb;
    unsigned short* G_c  = S_c;                    // gated, in-place over S
    unsigned short* H_c  = (unsigned short*)AOb;   // [Bc,1024], AO dead after proj_gate

    pack3<<<(int)(Bc / 2), 256, 0, stream>>>(
        (const float4*)(kin + boff * 512), (const float4*)(colr + boff * 512),
        (const float4*)(spi + boff * 512), (ushort4*)S_c);
    // fused qkv-gemm + attention: S -> AO
    qkv_attn<<<dim3(8, (int)(Bc / 32)), 256, 0, stream>>>(S_c, Wic, b_in, AO_c);
    // fused proj + residual + gate: AO,S -> G (in-place over S)
    proj_gate<<<(int)(Bc / 16), 256, 0, stream>>>(AO_c, S_c, Woc, b_out,
                                                  w_gate, b_gate, G_c);
    // h = silu(G @ w1^T + b1)   M=Bc N=1024 K=1536
    gemm_bt<EPI_SILU><<<dim3(8, (int)(Bc / 128)), 256, 0, stream>>>(
        G_c, W1c, b1, nullptr, H_c, 1536, 1024);
    // fused = LN(h @ w2^T + b2) -> out
    mlp2_ln<<<(int)(Bc / 64), 512, 0, stream>>>(H_c, W2c, b2, gamma, beta,
                                                out + boff * 512);
  }
}